// Round 10
// baseline (393.477 us; speedup 1.0000x reference)
//
#include <hip/hip_runtime.h>

#define BATCH 4096
#define TT 512
#define HH 64
#define XS 516     // x_s row stride in floats
#define HS 72      // h buffer row stride in bf16

typedef __attribute__((ext_vector_type(8))) short short8;
typedef __attribute__((ext_vector_type(4))) float floatx4;

__device__ __forceinline__ unsigned short f2bf(float f) {   // RNE f32->bf16
    unsigned u = __float_as_uint(f);
    u = u + 0x7FFFu + ((u >> 16) & 1u);
    return (unsigned short)(u >> 16);
}

// Cross-barrier software pipeline. Block = 16 batch rows as TWO groups of 8
// (two 16x16 tiles, rows at 4*(j>>1)+(j&1) -> lane slots r=0,1), 4 waves,
// grid 256 = 1 block/CU, no MFMA duplication (per-SIMD issue ~500 vs R9's 760).
// Interval k: act both groups (accs ready since LAST interval -> no dep wait),
// write h[k], ONE barrier, then read A-frags + issue step k+1's 16 MFMAs.
// The ds_read+MFMA latency completes under the next interval's act issue —
// the serial read->mfma->act->write chain of R1-R9 is pipelined away.
// Double-buffered h per group: write h[k] to buf[k&1], read after barrier from
// buf[k&1]; next write goes to buf[(k+1)&1] so laggard readers are safe.
__global__ __launch_bounds__(256, 1) void lstm_kernel(
    const float* __restrict__ x, const float* __restrict__ W_ih,
    const float* __restrict__ W_hh, const float* __restrict__ b_ih,
    const float* __restrict__ b_hh, const float* __restrict__ W_out,
    const float* __restrict__ b_out, float* __restrict__ out)
{
    __shared__ __align__(16) float x_s[16 * XS];             // 33 KB
    __shared__ __align__(16) unsigned short hg0[2][16 * HS]; // group0 h, dbuf
    __shared__ __align__(16) unsigned short hg1[2][16 * HS]; // group1 h, dbuf
    __shared__ __align__(16) float hf[16 * 65];

    const int tid = threadIdx.x;
    const int w = tid >> 6;       // wave 0..3 -> gate col-tiles {w,w+4,w+8,w+12}
    const int l = tid & 63;
    const int q = l >> 4;
    const int c = l & 15;
    const int n = 16 * w + c;     // hidden index this lane activates
    const int bbase = blockIdx.x * 16;

    // stage x[bbase..bbase+15][0..511] into LDS, coalesced float4
    for (int i = 0; i < 8; ++i) {
        int flat = i * 256 + tid;              // 2048 float4s
        int row = flat >> 7, c4 = flat & 127;
        const float4* xg = reinterpret_cast<const float4*>(x + (size_t)(bbase + row) * TT);
        float4 v = xg[c4];
        *reinterpret_cast<float4*>(&x_s[row * XS + c4 * 4]) = v;
    }
    for (int i = tid; i < 2 * 16 * HS; i += 256) { (&hg0[0][0])[i] = 0; (&hg1[0][0])[i] = 0; }

    // persistent B-fragments (shared by both groups): W_hh rows for g = 64*t+n
    short8 bfr[4][2];
    float wih[4], bb[4];
    for (int t = 0; t < 4; ++t) {
        int g = 64 * t + n;
        wih[t] = W_ih[g];
        bb[t] = b_ih[g] + b_hh[g];
        for (int ks = 0; ks < 2; ++ks) {
            const float* wp = W_hh + g * 64 + ks * 32 + q * 8;
            short8 v;
            #pragma unroll
            for (int j = 0; j < 8; ++j) v[j] = (short)f2bf(wp[j]);
            bfr[t][ks] = v;
        }
    }

    float cs0[2] = {0.f, 0.f}, cs1[2] = {0.f, 0.f};   // c-state per group, rows 2q+rr
    float hv0[2], hv1[2];                              // current h (register)

    floatx4 ac0[4], ac1[4];       // slots r=2,3 face zero A-rows: stay 0 forever
    #pragma unroll
    for (int t = 0; t < 4; ++t) { ac0[t] = floatx4{0.f,0.f,0.f,0.f}; ac1[t] = floatx4{0.f,0.f,0.f,0.f}; }

    const int aoff = c * HS + q * 8;      // A-frag LDS offset (shorts)
    const int woff = (4 * q) * HS + n;    // h write base; +HS for rr=1
    const float* xr0 = &x_s[(2 * q) * XS];        // group0 rows 2q, 2q+1
    const float* xr1 = &x_s[(8 + 2 * q) * XS];    // group1 rows 8+2q, 8+2q+1
    const float L1 = 1.44269504089f;      // log2(e)
    const float L2 = 2.88539008178f;      // 2*log2(e)

    __syncthreads();   // staging + zeroed h visible

    // Prologue: gates for step 0 = x_proj only (h_{-1}=0 -> MFMA contributes 0)
    {
        float a0 = xr0[0], a1 = xr0[XS], b0 = xr1[0], b1 = xr1[XS];
        #pragma unroll
        for (int t = 0; t < 4; ++t) {
            ac0[t][0] = fmaf(a0, wih[t], bb[t]); ac0[t][1] = fmaf(a1, wih[t], bb[t]);
            ac1[t][0] = fmaf(b0, wih[t], bb[t]); ac1[t][1] = fmaf(b1, wih[t], bb[t]);
        }
    }

    #define ACT(ACC, CST, HV) do {                                              \
        _Pragma("unroll")                                                       \
        for (int rr = 0; rr < 2; ++rr) {                                        \
            float gi = ACC[0][rr], gf = ACC[1][rr], gg = ACC[2][rr], go = ACC[3][rr]; \
            float ei = __builtin_amdgcn_exp2f(-L1 * gi);                        \
            float ef = __builtin_amdgcn_exp2f(-L1 * gf);                        \
            float eg = __builtin_amdgcn_exp2f( L2 * gg);                        \
            float eo = __builtin_amdgcn_exp2f(-L1 * go);                        \
            float pf1 = 1.f + ef, pig = (1.f + ei) * (1.f + eg);                \
            float num = fmaf(CST[rr], pig, (eg - 1.f) * pf1);                   \
            CST[rr] = num * __builtin_amdgcn_rcpf(pf1 * pig);                   \
            float ec = __builtin_amdgcn_exp2f(L2 * CST[rr]);                    \
            HV[rr] = (ec - 1.f) * __builtin_amdgcn_rcpf((1.f + eo) * (1.f + ec)); \
        } } while (0)

    for (int k = 0; k < TT - 1; ++k) {
        unsigned short* d0 = hg0[k & 1];
        unsigned short* d1 = hg1[k & 1];

        // acts: accs were filled by MFMAs issued before the previous barrier
        ACT(ac0, cs0, hv0);
        d0[woff] = f2bf(hv0[0]); d0[woff + HS] = f2bf(hv0[1]);
        ACT(ac1, cs1, hv1);
        d1[woff] = f2bf(hv1[0]); d1[woff + HS] = f2bf(hv1[1]);

        __syncthreads();

        // step k+1 gates: read h[k], init x_proj, issue MFMAs; consumed NEXT interval
        short8 a00 = *reinterpret_cast<const short8*>(d0 + aoff);
        short8 a01 = *reinterpret_cast<const short8*>(d0 + aoff + 32);
        short8 a10 = *reinterpret_cast<const short8*>(d1 + aoff);
        short8 a11 = *reinterpret_cast<const short8*>(d1 + aoff + 32);

        float xa0 = xr0[k + 1], xa1 = xr0[XS + k + 1];
        float xb0 = xr1[k + 1], xb1 = xr1[XS + k + 1];
        #pragma unroll
        for (int t = 0; t < 4; ++t) {
            ac0[t][0] = fmaf(xa0, wih[t], bb[t]); ac0[t][1] = fmaf(xa1, wih[t], bb[t]);
            ac1[t][0] = fmaf(xb0, wih[t], bb[t]); ac1[t][1] = fmaf(xb1, wih[t], bb[t]);
        }
        #pragma unroll
        for (int t = 0; t < 4; ++t) {
            ac0[t] = __builtin_amdgcn_mfma_f32_16x16x32_bf16(a00, bfr[t][0], ac0[t], 0, 0, 0);
            ac0[t] = __builtin_amdgcn_mfma_f32_16x16x32_bf16(a01, bfr[t][1], ac0[t], 0, 0, 0);
            ac1[t] = __builtin_amdgcn_mfma_f32_16x16x32_bf16(a10, bfr[t][0], ac1[t], 0, 0, 0);
            ac1[t] = __builtin_amdgcn_mfma_f32_16x16x32_bf16(a11, bfr[t][1], ac1[t], 0, 0, 0);
        }
    }

    // final step: act only (h[511] goes straight to the head)
    ACT(ac0, cs0, hv0);
    ACT(ac1, cs1, hv1);
    hf[(2 * q) * 65 + n] = hv0[0];
    hf[(2 * q + 1) * 65 + n] = hv0[1];
    hf[(8 + 2 * q) * 65 + n] = hv1[0];
    hf[(8 + 2 * q + 1) * 65 + n] = hv1[1];
    __syncthreads();

    // head: out[b][o] = sum_n hf[b][n]*W_out[o][n] + b_out[o]
    if (tid < 16 * 3) {
        int row = tid / 3, o = tid % 3;
        float s = b_out[o];
        #pragma unroll 8
        for (int k = 0; k < HH; ++k) s = fmaf(hf[row * 65 + k], W_out[o * 64 + k], s);
        out[(size_t)(bbase + row) * 3 + o] = s;
    }
    #undef ACT
}

extern "C" void kernel_launch(void* const* d_in, const int* in_sizes, int n_in,
                              void* d_out, int out_size, void* d_ws, size_t ws_size,
                              hipStream_t stream) {
    const float* x     = (const float*)d_in[0];
    const float* W_ih  = (const float*)d_in[1];
    const float* W_hh  = (const float*)d_in[2];
    const float* b_ih  = (const float*)d_in[3];
    const float* b_hh  = (const float*)d_in[4];
    const float* W_out = (const float*)d_in[5];
    const float* b_out = (const float*)d_in[6];
    float* out = (float*)d_out;
    hipLaunchKernelGGL(lstm_kernel, dim3(BATCH / 16), dim3(256), 0, stream,
                       x, W_ih, W_hh, b_ih, b_hh, W_out, b_out, out);
}

// Round 11
// 283.986 us; speedup vs baseline: 1.3855x; 1.3855x over previous
//
#include <hip/hip_runtime.h>

#define BATCH 4096
#define TT 512
#define HH 64
#define BT 8       // batch rows per block; batch j at tile row 4*(j>>1)+(j&1) -> valid C/D slots r=0,1
#define XS 516     // x_s row stride in floats
#define HS 72      // h buffer row stride in bf16

typedef __attribute__((ext_vector_type(8))) short short8;
typedef __attribute__((ext_vector_type(4))) float floatx4;

__device__ __forceinline__ unsigned short f2bf(float f) {   // RNE f32->bf16
    unsigned u = __float_as_uint(f);
    u = u + 0x7FFFu + ((u >> 16) & 1u);
    return (unsigned short)(u >> 16);
}

// R9 (best: 253 us) + two changes.
// (1) PHASE STAGGER: R9's counters showed VALU-busy(760) + MFMA-busy(271) +
//     idle(150) == wall(1190) exactly -> the two co-resident blocks (i, i+256
//     share a CU under round-robin XCD dispatch) run identical periodic code
//     launched simultaneously and phase-lock IN-PHASE: both do MFMA at the
//     same instant, both act at the same instant -> zero cross-wave overlap.
//     The late block sleeps ~576 cyc (half a step) once, before the loop,
//     forcing anti-phase so MFMA/ds of one hides under act of the other.
// (2) PRE-SCALED GATES: fold -log2e (i,f,o) / +2log2e (g) into W_ih/W_hh/b
//     at load time -> exp2 args come straight out of the MFMA, deleting
//     4 muls/cell from the act path.
__global__ __launch_bounds__(256, 2) void lstm_kernel(
    const float* __restrict__ x, const float* __restrict__ W_ih,
    const float* __restrict__ W_hh, const float* __restrict__ b_ih,
    const float* __restrict__ b_hh, const float* __restrict__ W_out,
    const float* __restrict__ b_out, float* __restrict__ out)
{
    __shared__ __align__(16) float x_s[BT * XS];             // 16.5 KB
    __shared__ __align__(16) unsigned short hb0[16 * HS];    // h_k, k even; rows m&2 stay 0
    __shared__ __align__(16) unsigned short hb1[16 * HS];    // h_k, k odd
    __shared__ __align__(16) float hf[BT * 65];

    const int tid = threadIdx.x;
    const int w = tid >> 6;       // wave 0..3 -> gate col-tiles {w,w+4,w+8,w+12}
    const int l = tid & 63;
    const int q = l >> 4;
    const int c = l & 15;
    const int n = 16 * w + c;     // hidden index this lane activates
    const int bbase = blockIdx.x * BT;

    // stage x[bbase..bbase+7][0..511] into LDS, coalesced float4
    for (int i = 0; i < 4; ++i) {
        int flat = i * 256 + tid;              // 1024 float4s
        int row = flat >> 7, c4 = flat & 127;
        const float4* xg = reinterpret_cast<const float4*>(x + (size_t)(bbase + row) * TT);
        float4 v = xg[c4];
        *reinterpret_cast<float4*>(&x_s[row * XS + c4 * 4]) = v;
    }
    for (int i = tid; i < 16 * HS; i += 256) { hb0[i] = 0; hb1[i] = 0; }

    const float L1 = 1.44269504089f;      // log2(e)
    const float L2 = 2.88539008178f;      // 2*log2(e)

    // persistent B-fragments: W_hh rows for gates g = 64*t + n, PRE-SCALED, bf16
    // t=0(i),1(f),3(o): scale -log2e ; t=2(g): scale +2*log2e
    short8 bfr[4][2];
    float wih[4], bb[4];
    for (int t = 0; t < 4; ++t) {
        float sc = (t == 2) ? L2 : -L1;
        int g = 64 * t + n;
        wih[t] = W_ih[g] * sc;
        bb[t] = (b_ih[g] + b_hh[g]) * sc;
        for (int ks = 0; ks < 2; ++ks) {
            const float* wp = W_hh + g * 64 + ks * 32 + q * 8;
            short8 v;
            #pragma unroll
            for (int j = 0; j < 8; ++j) v[j] = (short)f2bf(wp[j] * sc);
            bfr[t][ks] = v;
        }
    }

    float cst[2] = {0.f, 0.f};    // c-state, batch rows 2q+rr, hidden n
    float hvk[2] = {0.f, 0.f};    // last h, register-carried for the head

    floatx4 acc[4];               // slots r=2,3 face zero A-rows: init once, stay 0
    #pragma unroll
    for (int t = 0; t < 4; ++t) acc[t] = floatx4{0.f, 0.f, 0.f, 0.f};

    const int aoff = c * HS + q * 8;      // A-frag LDS offset (shorts)
    const int woff = (4 * q) * HS + n;    // h write base; +HS for rr=1
    const float* xrowA = &x_s[(2 * q) * XS];
    const float* xrowB = &x_s[(2 * q + 1) * XS];

    __syncthreads();   // staging + zeroed h0 visible

    // Anti-phase: the second co-resident block starts ~576 cyc late so its
    // MFMA phase overlaps the sibling's act phase (and stays offset — both
    // blocks have identical per-step duration).
    if (blockIdx.x >= (BATCH / BT / 2)) __builtin_amdgcn_s_sleep(9);

    for (int ts4 = 0; ts4 < TT; ts4 += 4) {
        float4 xa = *reinterpret_cast<const float4*>(xrowA + ts4);
        float4 xb = *reinterpret_cast<const float4*>(xrowB + ts4);
        #pragma unroll
        for (int u = 0; u < 4; ++u) {
            const unsigned short* src = (u & 1) ? hb1 : hb0;
            unsigned short* dst = (u & 1) ? hb0 : hb1;

            short8 a0 = *reinterpret_cast<const short8*>(src + aoff);
            short8 a1 = *reinterpret_cast<const short8*>(src + aoff + 32);

            float x0 = (&xa.x)[u], x1 = (&xb.x)[u];
            #pragma unroll
            for (int t = 0; t < 4; ++t) {
                acc[t][0] = fmaf(x0, wih[t], bb[t]);
                acc[t][1] = fmaf(x1, wih[t], bb[t]);
            }

            #pragma unroll
            for (int t = 0; t < 4; ++t) {
                acc[t] = __builtin_amdgcn_mfma_f32_16x16x32_bf16(a0, bfr[t][0], acc[t], 0, 0, 0);
                acc[t] = __builtin_amdgcn_mfma_f32_16x16x32_bf16(a1, bfr[t][1], acc[t], 0, 0, 0);
            }

            // gates arrive pre-scaled: ei=exp2(gi) etc. directly
            #pragma unroll
            for (int rr = 0; rr < 2; ++rr) {
                float ei = __builtin_amdgcn_exp2f(acc[0][rr]);
                float ef = __builtin_amdgcn_exp2f(acc[1][rr]);
                float eg = __builtin_amdgcn_exp2f(acc[2][rr]);
                float eo = __builtin_amdgcn_exp2f(acc[3][rr]);
                float pf1 = 1.f + ef, pig = (1.f + ei) * (1.f + eg);
                float num = fmaf(cst[rr], pig, (eg - 1.f) * pf1);
                cst[rr] = num * __builtin_amdgcn_rcpf(pf1 * pig);
                float ec = __builtin_amdgcn_exp2f(L2 * cst[rr]);
                float hv = (ec - 1.f) * __builtin_amdgcn_rcpf((1.f + eo) * (1.f + ec));
                hvk[rr] = hv;
                dst[woff + rr * HS] = f2bf(hv);
            }
            __syncthreads();
        }
    }

    hf[(2 * q) * 65 + n] = hvk[0];
    hf[(2 * q + 1) * 65 + n] = hvk[1];
    __syncthreads();

    // head: out[b][o] = sum_n hf[b][n]*W_out[o][n] + b_out[o]
    if (tid < BT * 3) {
        int row = tid / 3, o = tid % 3;
        float s = b_out[o];
        #pragma unroll 8
        for (int k = 0; k < HH; ++k) s = fmaf(hf[row * 65 + k], W_out[o * 64 + k], s);
        out[(size_t)(bbase + row) * 3 + o] = s;
    }
}

extern "C" void kernel_launch(void* const* d_in, const int* in_sizes, int n_in,
                              void* d_out, int out_size, void* d_ws, size_t ws_size,
                              hipStream_t stream) {
    const float* x     = (const float*)d_in[0];
    const float* W_ih  = (const float*)d_in[1];
    const float* W_hh  = (const float*)d_in[2];
    const float* b_ih  = (const float*)d_in[3];
    const float* b_hh  = (const float*)d_in[4];
    const float* W_out = (const float*)d_in[5];
    const float* b_out = (const float*)d_in[6];
    float* out = (float*)d_out;
    hipLaunchKernelGGL(lstm_kernel, dim3(BATCH / BT), dim3(256), 0, stream,
                       x, W_ih, W_hh, b_ih, b_hh, W_out, b_out, out);
}